// Round 1
// baseline (1405.454 us; speedup 1.0000x reference)
//
#include <hip/hip_runtime.h>
#include <hip/hip_bf16.h>
#include <math.h>

// Problem constants (fixed by the reference)
#define Bsz   8
#define LQ    9216
#define DIM   384
#define NH    6
#define NPTS  4
#define HD    64
#define H0    96
#define W0    96
#define NROWS (Bsz * LQ)        // 73728 (query rows == feat rows)
#define LN_EPS 1e-5f

// ---------------------------------------------------------------------------
// Kernel 1: per-row mean / rstd (one wave per row, 4 rows per block)
// ---------------------------------------------------------------------------
__global__ __launch_bounds__(256) void rowstats_kernel(
    const float* __restrict__ X, float* __restrict__ stats, int nrows)
{
    int wave = threadIdx.x >> 6;
    int lane = threadIdx.x & 63;
    int row  = blockIdx.x * 4 + wave;
    if (row >= nrows) return;
    const float* x = X + (size_t)row * DIM;
    float s = 0.f, sq = 0.f;
#pragma unroll
    for (int i = 0; i < DIM / 64; ++i) {
        float v = x[lane + i * 64];
        s += v; sq += v * v;
    }
#pragma unroll
    for (int off = 32; off > 0; off >>= 1) {
        s  += __shfl_down(s,  off, 64);
        sq += __shfl_down(sq, off, 64);
    }
    if (lane == 0) {
        float mu  = s * (1.f / DIM);
        float var = sq * (1.f / DIM) - mu * mu;
        stats[row * 2 + 0] = mu;
        stats[row * 2 + 1] = rsqrtf(var + LN_EPS);
    }
}

// ---------------------------------------------------------------------------
// Kernel 2: tiled fp32 GEMM  C = epilogue( LN(A) @ W + bias )
//   A: M x K row-major (raw; LN applied at load if stats != nullptr)
//   W: K x N row-major, N multiple of 4 (guarded for N < 64)
//   MODE 0: C = acc + bias
//   MODE 1: C = resid + gamma * (acc + bias)   (final residual GEMM)
// Block tile 64x64, 256 threads, 4x4 per thread, K-tile 16.
// ---------------------------------------------------------------------------
#define BM 64
#define BN 64
#define BK 16

template<int MODE>
__global__ __launch_bounds__(256) void gemm_ln_kernel(
    const float* __restrict__ A,
    const float* __restrict__ stats,
    const float* __restrict__ lnw, const float* __restrict__ lnb,
    const float* __restrict__ W,
    const float* __restrict__ bias,
    const float* __restrict__ resid,
    const float* __restrict__ gamma,
    float* __restrict__ C,
    int M, int N, int K)
{
    __shared__ __align__(16) float As[BK][BM + 4];  // +4: keep float4 row alignment
    __shared__ __align__(16) float Bs[BK][BN];

    const int row0 = blockIdx.x * BM;
    const int col0 = blockIdx.y * BN;

    const int t  = threadIdx.x;
    const int tx = t & 15;          // 0..15  -> 4 cols each
    const int ty = t >> 4;          // 0..15  -> 4 rows each

    // A-load mapping: thread loads A[row0 + t/4, k0 + (t%4)*4 .. +3]
    const int a_row = t >> 2;       // 0..63
    const int a_k4  = (t & 3) * 4;  // 0,4,8,12
    // B-load mapping: thread loads W[k0 + t/16, col0 + (t%16)*4 .. +3]
    const int b_kk  = t >> 4;       // 0..15
    const int b_c4  = (t & 15) * 4; // 0..60

    float mu = 0.f, rstd = 1.f;
    if (stats) {
        mu   = stats[(row0 + a_row) * 2 + 0];
        rstd = stats[(row0 + a_row) * 2 + 1];
    }

    float acc[4][4] = {};

    for (int k0 = 0; k0 < K; k0 += BK) {
        float4 av = *(const float4*)&A[(size_t)(row0 + a_row) * K + k0 + a_k4];
        if (stats) {
            float4 lw = *(const float4*)&lnw[k0 + a_k4];
            float4 lb = *(const float4*)&lnb[k0 + a_k4];
            av.x = (av.x - mu) * rstd * lw.x + lb.x;
            av.y = (av.y - mu) * rstd * lw.y + lb.y;
            av.z = (av.z - mu) * rstd * lw.z + lb.z;
            av.w = (av.w - mu) * rstd * lw.w + lb.w;
        }
        As[a_k4 + 0][a_row] = av.x;
        As[a_k4 + 1][a_row] = av.y;
        As[a_k4 + 2][a_row] = av.z;
        As[a_k4 + 3][a_row] = av.w;

        float4 bv = make_float4(0.f, 0.f, 0.f, 0.f);
        if (col0 + b_c4 < N)   // N is a multiple of 4
            bv = *(const float4*)&W[(size_t)(k0 + b_kk) * N + col0 + b_c4];
        *(float4*)&Bs[b_kk][b_c4] = bv;

        __syncthreads();
#pragma unroll
        for (int kk = 0; kk < BK; ++kk) {
            const float4 a4 = *(const float4*)&As[kk][ty * 4];
            const float4 b4 = *(const float4*)&Bs[kk][tx * 4];
            const float a[4] = {a4.x, a4.y, a4.z, a4.w};
            const float b[4] = {b4.x, b4.y, b4.z, b4.w};
#pragma unroll
            for (int i = 0; i < 4; ++i)
#pragma unroll
                for (int j = 0; j < 4; ++j)
                    acc[i][j] = fmaf(a[i], b[j], acc[i][j]);
        }
        __syncthreads();
    }

    const int c = col0 + tx * 4;
    if (c < N) {
#pragma unroll
        for (int i = 0; i < 4; ++i) {
            const int r = row0 + ty * 4 + i;
            float4 v;
            v.x = acc[i][0] + bias[c + 0];
            v.y = acc[i][1] + bias[c + 1];
            v.z = acc[i][2] + bias[c + 2];
            v.w = acc[i][3] + bias[c + 3];
            if (MODE == 1) {
                float4 q4 = *(const float4*)&resid[(size_t)r * N + c];
                v.x = q4.x + gamma[c + 0] * v.x;
                v.y = q4.y + gamma[c + 1] * v.y;
                v.z = q4.z + gamma[c + 2] * v.z;
                v.w = q4.w + gamma[c + 3] * v.w;
            }
            *(float4*)&C[(size_t)r * N + c] = v;
        }
    }
}

// ---------------------------------------------------------------------------
// Kernel 3: in-place loc transform + softmax
//   offbuf (nrows x 48): off -> x*W - 0.5, y*H - 0.5 (pre-scaled coords)
//   attbuf (nrows x 24): logits -> softmax over the 4 points per head
// One thread per (row, head).
// ---------------------------------------------------------------------------
__global__ __launch_bounds__(256) void locsoftmax_kernel(
    float* __restrict__ offbuf, float* __restrict__ attbuf,
    const float* __restrict__ refpts, int nrows)
{
    int gid = blockIdx.x * blockDim.x + threadIdx.x;
    if (gid >= nrows * NH) return;
    int row = gid / NH;
    int h   = gid % NH;

    const float rx = refpts[row * 2 + 0];
    const float ry = refpts[row * 2 + 1];

    float* off = offbuf + (size_t)row * (NH * NPTS * 2) + h * (NPTS * 2);
    float* att = attbuf + (size_t)row * (NH * NPTS)     + h * NPTS;

    float l0 = att[0], l1 = att[1], l2 = att[2], l3 = att[3];
    float m  = fmaxf(fmaxf(l0, l1), fmaxf(l2, l3));
    float e0 = expf(l0 - m), e1 = expf(l1 - m), e2 = expf(l2 - m), e3 = expf(l3 - m);
    float inv = 1.f / (e0 + e1 + e2 + e3);
    att[0] = e0 * inv; att[1] = e1 * inv; att[2] = e2 * inv; att[3] = e3 * inv;

#pragma unroll
    for (int p = 0; p < NPTS; ++p) {
        float ox = off[p * 2 + 0];
        float oy = off[p * 2 + 1];
        // loc = ref + off/norm ; x = loc*W - 0.5
        float x = (rx + ox * (1.f / W0)) * (float)W0 - 0.5f;
        float y = (ry + oy * (1.f / H0)) * (float)H0 - 0.5f;
        off[p * 2 + 0] = x;
        off[p * 2 + 1] = y;
    }
}

// ---------------------------------------------------------------------------
// Kernel 4: deformable sampling. One wave per (row, head); lane = channel d.
//   value: (B, H0*W0, NH*HD) row-major; out: (nrows, 384)
// ---------------------------------------------------------------------------
__global__ __launch_bounds__(256) void sample_kernel(
    const float* __restrict__ value,
    const float* __restrict__ sloc,   // (nrows, NH, NPTS, 2) pre-scaled
    const float* __restrict__ attw,   // (nrows, NH, NPTS)
    float* __restrict__ out,
    int nrows)
{
    int wave = threadIdx.x >> 6;
    int lane = threadIdx.x & 63;
    int task = blockIdx.x * 4 + wave;         // (row, h)
    if (task >= nrows * NH) return;
    int row = task / NH;
    int h   = task % NH;
    int b   = row / LQ;

    const float* vbase = value + (size_t)b * (H0 * W0) * DIM + h * HD;
    const float* sl = sloc + (size_t)task * (NPTS * 2);
    const float* aw = attw + (size_t)task * NPTS;

    float acc = 0.f;
#pragma unroll
    for (int p = 0; p < NPTS; ++p) {
        float x = sl[p * 2 + 0];
        float y = sl[p * 2 + 1];
        float w = aw[p];
        float xf = floorf(x), yf = floorf(y);
        int   x0 = (int)xf,   y0 = (int)yf;
        float fx = x - xf,    fy = y - yf;
        float w00 = (1.f - fx) * (1.f - fy);
        float w10 = fx * (1.f - fy);
        float w01 = (1.f - fx) * fy;
        float w11 = fx * fy;
        if ((unsigned)x0 < W0 && (unsigned)y0 < H0)
            acc += w * w00 * vbase[(size_t)(y0 * W0 + x0) * DIM + lane];
        if ((unsigned)(x0 + 1) < W0 && (unsigned)y0 < H0)
            acc += w * w10 * vbase[(size_t)(y0 * W0 + x0 + 1) * DIM + lane];
        if ((unsigned)x0 < W0 && (unsigned)(y0 + 1) < H0)
            acc += w * w01 * vbase[(size_t)((y0 + 1) * W0 + x0) * DIM + lane];
        if ((unsigned)(x0 + 1) < W0 && (unsigned)(y0 + 1) < H0)
            acc += w * w11 * vbase[(size_t)((y0 + 1) * W0 + x0 + 1) * DIM + lane];
    }
    out[(size_t)row * DIM + h * HD + lane] = acc;
}

// ---------------------------------------------------------------------------
// Launch
// ---------------------------------------------------------------------------
extern "C" void kernel_launch(void* const* d_in, const int* in_sizes, int n_in,
                              void* d_out, int out_size, void* d_ws, size_t ws_size,
                              hipStream_t stream)
{
    const float* query   = (const float*)d_in[0];
    const float* refpts  = (const float*)d_in[1];
    const float* feat    = (const float*)d_in[2];
    // d_in[3] spatial_shapes, d_in[4] level_start_index: compile-time constants
    const float* qn_w    = (const float*)d_in[5];
    const float* qn_b    = (const float*)d_in[6];
    const float* fn_w    = (const float*)d_in[7];
    const float* fn_b    = (const float*)d_in[8];
    const float* w_value = (const float*)d_in[9];
    const float* b_value = (const float*)d_in[10];
    const float* w_off   = (const float*)d_in[11];
    const float* b_off   = (const float*)d_in[12];
    const float* w_attn  = (const float*)d_in[13];
    const float* b_attn  = (const float*)d_in[14];
    const float* w_out   = (const float*)d_in[15];
    const float* b_out   = (const float*)d_in[16];
    const float* gamma   = (const float*)d_in[17];

    float* ws = (float*)d_ws;
    float* statsQ   = ws;                                  // NROWS*2
    float* statsF   = statsQ + (size_t)NROWS * 2;          // NROWS*2
    float* value    = statsF + (size_t)NROWS * 2;          // NROWS*384
    float* offbuf   = value  + (size_t)NROWS * DIM;        // NROWS*48
    float* attbuf   = offbuf + (size_t)NROWS * NH * NPTS * 2; // NROWS*24
    float* attn_out = attbuf + (size_t)NROWS * NH * NPTS;  // NROWS*384
    float* outp     = (float*)d_out;

    // 1. row stats for both LayerNorms
    rowstats_kernel<<<NROWS / 4, 256, 0, stream>>>(query, statsQ, NROWS);
    rowstats_kernel<<<NROWS / 4, 256, 0, stream>>>(feat,  statsF, NROWS);

    // 2. value = LN(feat) @ w_value + b_value   (N = 384)
    dim3 gBig(NROWS / BM, DIM / BN);
    gemm_ln_kernel<0><<<gBig, 256, 0, stream>>>(
        feat, statsF, fn_w, fn_b, w_value, b_value, nullptr, nullptr,
        value, NROWS, DIM, DIM);

    // 3. off = LN(q) @ w_off + b_off   (N = 48)
    dim3 gSmall(NROWS / BM, 1);
    gemm_ln_kernel<0><<<gSmall, 256, 0, stream>>>(
        query, statsQ, qn_w, qn_b, w_off, b_off, nullptr, nullptr,
        offbuf, NROWS, NH * NPTS * 2, DIM);

    // 4. attn logits = LN(q) @ w_attn + b_attn   (N = 24)
    gemm_ln_kernel<0><<<gSmall, 256, 0, stream>>>(
        query, statsQ, qn_w, qn_b, w_attn, b_attn, nullptr, nullptr,
        attbuf, NROWS, NH * NPTS, DIM);

    // 5. sample coords + softmax (in place)
    locsoftmax_kernel<<<(NROWS * NH) / 256, 256, 0, stream>>>(
        offbuf, attbuf, refpts, NROWS);

    // 6. deformable bilinear sampling
    sample_kernel<<<(NROWS * NH) / 4, 256, 0, stream>>>(
        value, offbuf, attbuf, attn_out, NROWS);

    // 7. out = query + gamma * (attn_out @ w_out + b_out)
    gemm_ln_kernel<1><<<gBig, 256, 0, stream>>>(
        attn_out, nullptr, nullptr, nullptr, w_out, b_out, query, gamma,
        outp, NROWS, DIM, DIM);
}

// Round 2
// 801.021 us; speedup vs baseline: 1.7546x; 1.7546x over previous
//
#include <hip/hip_runtime.h>
#include <hip/hip_bf16.h>
#include <math.h>

// Problem constants (fixed by the reference)
#define Bsz   8
#define LQ    9216
#define DIM   384
#define NH    6
#define NPTS  4
#define HD    64
#define H0    96
#define W0    96
#define NROWS (Bsz * LQ)        // 73728
#define LN_EPS 1e-5f

typedef __attribute__((ext_vector_type(8))) short short8;   // 8 bf16 = 4 VGPRs
typedef __attribute__((ext_vector_type(4))) float f32x4;

__device__ __forceinline__ void load_lds16(const void* g, void* l) {
    __builtin_amdgcn_global_load_lds(
        (const __attribute__((address_space(1))) void*)g,
        (__attribute__((address_space(3))) void*)l,
        16, 0, 0);
}

// ---------------------------------------------------------------------------
// Kernel 1: fused LayerNorm -> bf16.  One wave per row, 4 rows/block.
// ---------------------------------------------------------------------------
__global__ __launch_bounds__(256) void lnorm_kernel(
    const float* __restrict__ X,
    const float* __restrict__ w, const float* __restrict__ bvec,
    __hip_bfloat16* __restrict__ Y)
{
    int wave = threadIdx.x >> 6, lane = threadIdx.x & 63;
    int row = blockIdx.x * 4 + wave;
    const float* x = X + (size_t)row * DIM;
    float2 v[3];
    float s = 0.f, sq = 0.f;
#pragma unroll
    for (int i = 0; i < 3; ++i) {
        v[i] = *(const float2*)&x[lane * 2 + i * 128];
        s  += v[i].x + v[i].y;
        sq += v[i].x * v[i].x + v[i].y * v[i].y;
    }
#pragma unroll
    for (int off = 1; off < 64; off <<= 1) {
        s  += __shfl_xor(s,  off, 64);
        sq += __shfl_xor(sq, off, 64);
    }
    float mu   = s * (1.f / DIM);
    float rstd = rsqrtf(sq * (1.f / DIM) - mu * mu + LN_EPS);
#pragma unroll
    for (int i = 0; i < 3; ++i) {
        int p = lane * 2 + i * 128;
        float2 ww = *(const float2*)&w[p];
        float2 bb = *(const float2*)&bvec[p];
        __hip_bfloat162 o;
        o.x = __float2bfloat16((v[i].x - mu) * rstd * ww.x + bb.x);
        o.y = __float2bfloat16((v[i].y - mu) * rstd * ww.y + bb.y);
        *(__hip_bfloat162*)&Y[(size_t)row * DIM + p] = o;
    }
}

// ---------------------------------------------------------------------------
// Kernel 2: weight transpose + cvt to bf16 [N][K] layout (one-shot, tiny).
//   WtV: 384x384 from w_value ; WtO: 384x384 from w_out ;
//   WtS: 128x384, rows 0..47 = w_off cols, rows 48..71 = w_attn cols, rest 0.
// ---------------------------------------------------------------------------
__global__ __launch_bounds__(256) void wtrans_kernel(
    const float* __restrict__ wv, const float* __restrict__ wo,
    const float* __restrict__ woff, const float* __restrict__ watt,
    __hip_bfloat16* __restrict__ WtV, __hip_bfloat16* __restrict__ WtO,
    __hip_bfloat16* __restrict__ WtS)
{
    int gid = blockIdx.x * 256 + threadIdx.x;
    if (gid < 147456) {
        int n = gid / 384, k = gid % 384;
        WtV[gid] = __float2bfloat16(wv[k * 384 + n]);
    } else if (gid < 294912) {
        int i = gid - 147456;
        int n = i / 384, k = i % 384;
        WtO[i] = __float2bfloat16(wo[k * 384 + n]);
    } else {
        int i = gid - 294912;
        int n = i / 384, k = i % 384;
        float v = 0.f;
        if (n < 48)      v = woff[k * 48 + n];
        else if (n < 72) v = watt[k * 24 + (n - 48)];
        WtS[i] = __float2bfloat16(v);
    }
}

// ---------------------------------------------------------------------------
// Kernel 3: bf16 MFMA GEMM (m97 structure): C = A @ Bt^T (+epilogue)
//   A : [M][384] bf16 row-major. Bt : [N][384] bf16 (pre-transposed weight).
//   128x128 block tile, BK=32, 256 thr = 4 waves (2x2), each wave 64x64 via
//   4x4 tiles of v_mfma_f32_16x16x32_bf16. global_load_lds width=16 staging.
//   MODE 0: value GEMM  -> bf16 store, transposed layout (b,h,pix,64)
//   MODE 1: final GEMM  -> fp32 store, out = resid + gamma*(acc+bias)
//   MODE 2: off+attn    -> cols 0..47 -> offbuf, 48..71 -> attbuf (fp32)
// ---------------------------------------------------------------------------
template<int MODE>
__global__ __launch_bounds__(256) void gemm16_kernel(
    const __hip_bfloat16* __restrict__ A,
    const __hip_bfloat16* __restrict__ Bt,
    const float* __restrict__ bias,
    const float* __restrict__ bias2,
    const float* __restrict__ resid,
    const float* __restrict__ gamma,
    void* __restrict__ out0,
    void* __restrict__ out1)
{
    __shared__ short As[128 * 32];
    __shared__ short Bs[128 * 32];

    const int t    = threadIdx.x;
    const int lane = t & 63;
    const int w    = t >> 6;
    const int wm   = w >> 1, wn = w & 1;
    const int row0 = blockIdx.x * 128;
    const int col0 = blockIdx.y * 128;
    const int lm   = lane & 15, lq = lane >> 4;

    f32x4 acc[4][4];
#pragma unroll
    for (int i = 0; i < 4; ++i)
#pragma unroll
        for (int j = 0; j < 4; ++j)
            acc[i][j] = (f32x4){0.f, 0.f, 0.f, 0.f};

    for (int k0 = 0; k0 < 384; k0 += 32) {
        // ---- stage 128x32 bf16 tiles of A and Bt via global_load_lds ----
#pragma unroll
        for (int j = 0; j < 2; ++j) {
            int seg = w * 2 + j;                 // 0..7, 16 rows each
            int rr  = seg * 16 + (lane >> 2);
            const char* gA = (const char*)(A  + ((size_t)(row0 + rr) * 384 + k0)) + (lane & 3) * 16;
            const char* gB = (const char*)(Bt + ((size_t)(col0 + rr) * 384 + k0)) + (lane & 3) * 16;
            load_lds16(gA, (char*)As + seg * 1024);
            load_lds16(gB, (char*)Bs + seg * 1024);
        }
        __syncthreads();

        short8 af[4], bf[4];
#pragma unroll
        for (int i = 0; i < 4; ++i) {
            af[i] = *(const short8*)&As[(wm * 64 + i * 16 + lm) * 32 + lq * 8];
            bf[i] = *(const short8*)&Bs[(wn * 64 + i * 16 + lm) * 32 + lq * 8];
        }
#pragma unroll
        for (int i = 0; i < 4; ++i)
#pragma unroll
            for (int j = 0; j < 4; ++j)
                acc[i][j] = __builtin_amdgcn_mfma_f32_16x16x32_bf16(af[i], bf[j], acc[i][j], 0, 0, 0);
        __syncthreads();
    }

    // ---- epilogue ----
#pragma unroll
    for (int i = 0; i < 4; ++i) {
#pragma unroll
        for (int j = 0; j < 4; ++j) {
            const int col = col0 + wn * 64 + j * 16 + lm;
#pragma unroll
            for (int r = 0; r < 4; ++r) {
                const int row = row0 + wm * 64 + i * 16 + lq * 4 + r;
                float v = acc[i][j][r];
                if (MODE == 0) {
                    v += bias[col];
                    int b = row / LQ, pix = row - b * LQ;
                    int h = col >> 6, d = col & 63;
                    ((__hip_bfloat16*)out0)[(((size_t)(b * NH + h)) * LQ + pix) * 64 + d] =
                        __float2bfloat16(v);
                } else if (MODE == 1) {
                    v += bias[col];
                    size_t o = (size_t)row * 384 + col;
                    ((float*)out0)[o] = resid[o] + gamma[col] * v;
                } else {
                    if (col < 48)
                        ((float*)out0)[(size_t)row * 48 + col] = v + bias[col];
                    else if (col < 72)
                        ((float*)out1)[(size_t)row * 24 + (col - 48)] = v + bias2[col - 48];
                }
            }
        }
    }
}

// ---------------------------------------------------------------------------
// Kernel 4: in-place loc transform + softmax (per (row, head) thread)
// ---------------------------------------------------------------------------
__global__ __launch_bounds__(256) void locsoftmax_kernel(
    float* __restrict__ offbuf, float* __restrict__ attbuf,
    const float* __restrict__ refpts)
{
    int gid = blockIdx.x * blockDim.x + threadIdx.x;
    int row = gid / NH;
    int h   = gid % NH;

    const float rx = refpts[row * 2 + 0];
    const float ry = refpts[row * 2 + 1];

    float* off = offbuf + (size_t)row * (NH * NPTS * 2) + h * (NPTS * 2);
    float* att = attbuf + (size_t)row * (NH * NPTS)     + h * NPTS;

    float l0 = att[0], l1 = att[1], l2 = att[2], l3 = att[3];
    float m  = fmaxf(fmaxf(l0, l1), fmaxf(l2, l3));
    float e0 = expf(l0 - m), e1 = expf(l1 - m), e2 = expf(l2 - m), e3 = expf(l3 - m);
    float inv = 1.f / (e0 + e1 + e2 + e3);
    att[0] = e0 * inv; att[1] = e1 * inv; att[2] = e2 * inv; att[3] = e3 * inv;

#pragma unroll
    for (int p = 0; p < NPTS; ++p) {
        float ox = off[p * 2 + 0];
        float oy = off[p * 2 + 1];
        off[p * 2 + 0] = (rx + ox * (1.f / W0)) * (float)W0 - 0.5f;
        off[p * 2 + 1] = (ry + oy * (1.f / H0)) * (float)H0 - 0.5f;
    }
}

// ---------------------------------------------------------------------------
// Kernel 5: deformable sampling on (b,h,pix,64) bf16 value planes.
//   task = ((b*NH+h)*LQ + q)  -> bh-major ordering so consecutive blocks hit
//   the same 1.18 MB L2-resident plane. One wave per task, lane = channel.
// ---------------------------------------------------------------------------
__global__ __launch_bounds__(256) void sample_kernel(
    const __hip_bfloat16* __restrict__ vt,
    const float* __restrict__ sloc,   // (row, NH, NPTS, 2) pre-scaled coords
    const float* __restrict__ attw,   // (row, NH, NPTS)
    __hip_bfloat16* __restrict__ out) // (row, 384)
{
    int wave = threadIdx.x >> 6, lane = threadIdx.x & 63;
    int task = blockIdx.x * 4 + wave;
    int bh = task / LQ, q = task - bh * LQ;
    int b  = bh / NH,  h = bh - b * NH;
    int row = b * LQ + q;

    const __hip_bfloat16* vbase = vt + ((size_t)bh * LQ) * 64;
    const float* sl = sloc + ((size_t)row * NH + h) * (NPTS * 2);
    const float* aw = attw + ((size_t)row * NH + h) * NPTS;

    float acc = 0.f;
#pragma unroll
    for (int p = 0; p < NPTS; ++p) {
        float x = sl[p * 2 + 0];
        float y = sl[p * 2 + 1];
        float wgt = aw[p];
        float xf = floorf(x), yf = floorf(y);
        int   x0 = (int)xf,   y0 = (int)yf;
        float fx = x - xf,    fy = y - yf;
        float w00 = (1.f - fx) * (1.f - fy) * wgt;
        float w10 = fx * (1.f - fy) * wgt;
        float w01 = (1.f - fx) * fy * wgt;
        float w11 = fx * fy * wgt;
        if ((unsigned)x0 < W0 && (unsigned)y0 < H0)
            acc += w00 * __bfloat162float(vbase[(size_t)(y0 * W0 + x0) * 64 + lane]);
        if ((unsigned)(x0 + 1) < W0 && (unsigned)y0 < H0)
            acc += w10 * __bfloat162float(vbase[(size_t)(y0 * W0 + x0 + 1) * 64 + lane]);
        if ((unsigned)x0 < W0 && (unsigned)(y0 + 1) < H0)
            acc += w01 * __bfloat162float(vbase[(size_t)((y0 + 1) * W0 + x0) * 64 + lane]);
        if ((unsigned)(x0 + 1) < W0 && (unsigned)(y0 + 1) < H0)
            acc += w11 * __bfloat162float(vbase[(size_t)((y0 + 1) * W0 + x0 + 1) * 64 + lane]);
    }
    out[(size_t)row * DIM + h * HD + lane] = __float2bfloat16(acc);
}

// ---------------------------------------------------------------------------
// Launch
// ---------------------------------------------------------------------------
extern "C" void kernel_launch(void* const* d_in, const int* in_sizes, int n_in,
                              void* d_out, int out_size, void* d_ws, size_t ws_size,
                              hipStream_t stream)
{
    const float* query   = (const float*)d_in[0];
    const float* refpts  = (const float*)d_in[1];
    const float* feat    = (const float*)d_in[2];
    const float* qn_w    = (const float*)d_in[5];
    const float* qn_b    = (const float*)d_in[6];
    const float* fn_w    = (const float*)d_in[7];
    const float* fn_b    = (const float*)d_in[8];
    const float* w_value = (const float*)d_in[9];
    const float* b_value = (const float*)d_in[10];
    const float* w_off   = (const float*)d_in[11];
    const float* b_off   = (const float*)d_in[12];
    const float* w_attn  = (const float*)d_in[13];
    const float* b_attn  = (const float*)d_in[14];
    const float* w_out   = (const float*)d_in[15];
    const float* b_out   = (const float*)d_in[16];
    const float* gamma   = (const float*)d_in[17];

    char* wsb = (char*)d_ws;
    __hip_bfloat16* Q16    = (__hip_bfloat16*)wsb;                 // 56.6 MB
    __hip_bfloat16* F16    = (__hip_bfloat16*)(wsb + 56623104);    // 56.6 MB
    __hip_bfloat16* vtrans = (__hip_bfloat16*)(wsb + 113246208);   // 56.6 MB
    __hip_bfloat16* att16  = (__hip_bfloat16*)(wsb + 169869312);   // 56.6 MB
    float*          offbuf = (float*)(wsb + 226492416);            // 14.2 MB
    float*          attbuf = (float*)(wsb + 240648192);            // 7.1 MB
    __hip_bfloat16* WtV    = (__hip_bfloat16*)(wsb + 247726080);   // 294912 B
    __hip_bfloat16* WtO    = (__hip_bfloat16*)(wsb + 248020992);   // 294912 B
    __hip_bfloat16* WtS    = (__hip_bfloat16*)(wsb + 248315904);   // 98304 B
    float* outp = (float*)d_out;

    // 1-2. LayerNorms -> bf16
    lnorm_kernel<<<NROWS / 4, 256, 0, stream>>>(query, qn_w, qn_b, Q16);
    lnorm_kernel<<<NROWS / 4, 256, 0, stream>>>(feat,  fn_w, fn_b, F16);

    // 3. weight transpose/cvt
    wtrans_kernel<<<1344, 256, 0, stream>>>(w_value, w_out, w_off, w_attn,
                                            WtV, WtO, WtS);

    // 4. value = LN(feat) @ w_value + b_value  -> bf16 (b,h,pix,64) layout
    gemm16_kernel<0><<<dim3(NROWS / 128, 3), 256, 0, stream>>>(
        F16, WtV, b_value, nullptr, nullptr, nullptr, vtrans, nullptr);

    // 5. off/attn logits = LN(q) @ [w_off|w_attn]  (one 128-col MFMA GEMM)
    gemm16_kernel<2><<<dim3(NROWS / 128, 1), 256, 0, stream>>>(
        Q16, WtS, b_off, b_attn, nullptr, nullptr, offbuf, attbuf);

    // 6. sample coords + softmax (in place)
    locsoftmax_kernel<<<(NROWS * NH) / 256, 256, 0, stream>>>(
        offbuf, attbuf, refpts);

    // 7. deformable bilinear sampling -> bf16 attn_out
    sample_kernel<<<(NROWS * NH) / 4, 256, 0, stream>>>(
        vtrans, offbuf, attbuf, att16);

    // 8. out = query + gamma * (attn_out @ w_out + b_out)
    gemm16_kernel<1><<<dim3(NROWS / 128, 3), 256, 0, stream>>>(
        att16, WtO, b_out, nullptr, query, gamma, outp, nullptr);
}

// Round 3
// 536.392 us; speedup vs baseline: 2.6202x; 1.4933x over previous
//
#include <hip/hip_runtime.h>
#include <hip/hip_bf16.h>
#include <math.h>

// Problem constants (fixed by the reference)
#define Bsz   8
#define LQ    9216
#define DIM   384
#define NH    6
#define NPTS  4
#define HD    64
#define H0    96
#define W0    96
#define NROWS (Bsz * LQ)        // 73728
#define LN_EPS 1e-5f

typedef __attribute__((ext_vector_type(8))) short short8;   // 8 bf16 = 4 VGPRs
typedef __attribute__((ext_vector_type(4))) float f32x4;

__device__ __forceinline__ void load_lds16(const void* g, void* l) {
    __builtin_amdgcn_global_load_lds(
        (const __attribute__((address_space(1))) void*)g,
        (__attribute__((address_space(3))) void*)l,
        16, 0, 0);
}

__device__ __forceinline__ float bf_lo(unsigned u) { return __uint_as_float(u << 16); }
__device__ __forceinline__ float bf_hi(unsigned u) { return __uint_as_float(u & 0xffff0000u); }

// ---------------------------------------------------------------------------
// Kernel 1: fused LayerNorm -> bf16.  One wave per row, 4 rows/block.
// ---------------------------------------------------------------------------
__global__ __launch_bounds__(256) void lnorm_kernel(
    const float* __restrict__ X,
    const float* __restrict__ w, const float* __restrict__ bvec,
    __hip_bfloat16* __restrict__ Y)
{
    int wave = threadIdx.x >> 6, lane = threadIdx.x & 63;
    int row = blockIdx.x * 4 + wave;
    const float* x = X + (size_t)row * DIM;
    float2 v[3];
    float s = 0.f, sq = 0.f;
#pragma unroll
    for (int i = 0; i < 3; ++i) {
        v[i] = *(const float2*)&x[lane * 2 + i * 128];
        s  += v[i].x + v[i].y;
        sq += v[i].x * v[i].x + v[i].y * v[i].y;
    }
#pragma unroll
    for (int off = 1; off < 64; off <<= 1) {
        s  += __shfl_xor(s,  off, 64);
        sq += __shfl_xor(sq, off, 64);
    }
    float mu   = s * (1.f / DIM);
    float rstd = rsqrtf(sq * (1.f / DIM) - mu * mu + LN_EPS);
#pragma unroll
    for (int i = 0; i < 3; ++i) {
        int p = lane * 2 + i * 128;
        float2 ww = *(const float2*)&w[p];
        float2 bb = *(const float2*)&bvec[p];
        __hip_bfloat162 o;
        o.x = __float2bfloat16((v[i].x - mu) * rstd * ww.x + bb.x);
        o.y = __float2bfloat16((v[i].y - mu) * rstd * ww.y + bb.y);
        *(__hip_bfloat162*)&Y[(size_t)row * DIM + p] = o;
    }
}

// ---------------------------------------------------------------------------
// Kernel 2: weight transpose + cvt to bf16 [N][K] layout (one-shot, tiny).
// ---------------------------------------------------------------------------
__global__ __launch_bounds__(256) void wtrans_kernel(
    const float* __restrict__ wv, const float* __restrict__ wo,
    const float* __restrict__ woff, const float* __restrict__ watt,
    __hip_bfloat16* __restrict__ WtV, __hip_bfloat16* __restrict__ WtO,
    __hip_bfloat16* __restrict__ WtS)
{
    int gid = blockIdx.x * 256 + threadIdx.x;
    if (gid < 147456) {
        int n = gid / 384, k = gid % 384;
        WtV[gid] = __float2bfloat16(wv[k * 384 + n]);
    } else if (gid < 294912) {
        int i = gid - 147456;
        int n = i / 384, k = i % 384;
        WtO[i] = __float2bfloat16(wo[k * 384 + n]);
    } else {
        int i = gid - 294912;
        int n = i / 384, k = i % 384;
        float v = 0.f;
        if (n < 48)      v = woff[k * 48 + n];
        else if (n < 72) v = watt[k * 24 + (n - 48)];
        WtS[i] = __float2bfloat16(v);
    }
}

// ---------------------------------------------------------------------------
// Kernel 3: bf16 MFMA GEMM (m97 structure): C = A @ Bt^T (+epilogue)
//   MODE 0: value GEMM  -> bf16 store, transposed layout (b,h,pix,64)
//   MODE 1: final GEMM  -> fp32 store, out = resid + gamma*(acc+bias)
//   MODE 2: off+attn    -> cols 0..47 -> offbuf, 48..71 -> attbuf (fp32)
// ---------------------------------------------------------------------------
template<int MODE>
__global__ __launch_bounds__(256) void gemm16_kernel(
    const __hip_bfloat16* __restrict__ A,
    const __hip_bfloat16* __restrict__ Bt,
    const float* __restrict__ bias,
    const float* __restrict__ bias2,
    const float* __restrict__ resid,
    const float* __restrict__ gamma,
    void* __restrict__ out0,
    void* __restrict__ out1)
{
    __shared__ short As[128 * 32];
    __shared__ short Bs[128 * 32];

    const int t    = threadIdx.x;
    const int lane = t & 63;
    const int w    = t >> 6;
    const int wm   = w >> 1, wn = w & 1;
    const int row0 = blockIdx.x * 128;
    const int col0 = blockIdx.y * 128;
    const int lm   = lane & 15, lq = lane >> 4;

    f32x4 acc[4][4];
#pragma unroll
    for (int i = 0; i < 4; ++i)
#pragma unroll
        for (int j = 0; j < 4; ++j)
            acc[i][j] = (f32x4){0.f, 0.f, 0.f, 0.f};

    for (int k0 = 0; k0 < 384; k0 += 32) {
#pragma unroll
        for (int j = 0; j < 2; ++j) {
            int seg = w * 2 + j;                 // 0..7, 16 rows each
            int rr  = seg * 16 + (lane >> 2);
            const char* gA = (const char*)(A  + ((size_t)(row0 + rr) * 384 + k0)) + (lane & 3) * 16;
            const char* gB = (const char*)(Bt + ((size_t)(col0 + rr) * 384 + k0)) + (lane & 3) * 16;
            load_lds16(gA, (char*)As + seg * 1024);
            load_lds16(gB, (char*)Bs + seg * 1024);
        }
        __syncthreads();

        short8 af[4], bf[4];
#pragma unroll
        for (int i = 0; i < 4; ++i) {
            af[i] = *(const short8*)&As[(wm * 64 + i * 16 + lm) * 32 + lq * 8];
            bf[i] = *(const short8*)&Bs[(wn * 64 + i * 16 + lm) * 32 + lq * 8];
        }
#pragma unroll
        for (int i = 0; i < 4; ++i)
#pragma unroll
            for (int j = 0; j < 4; ++j)
                acc[i][j] = __builtin_amdgcn_mfma_f32_16x16x32_bf16(af[i], bf[j], acc[i][j], 0, 0, 0);
        __syncthreads();
    }

#pragma unroll
    for (int i = 0; i < 4; ++i) {
#pragma unroll
        for (int j = 0; j < 4; ++j) {
            const int col = col0 + wn * 64 + j * 16 + lm;
#pragma unroll
            for (int r = 0; r < 4; ++r) {
                const int row = row0 + wm * 64 + i * 16 + lq * 4 + r;
                float v = acc[i][j][r];
                if (MODE == 0) {
                    v += bias[col];
                    int b = row / LQ, pix = row - b * LQ;
                    int h = col >> 6, d = col & 63;
                    ((__hip_bfloat16*)out0)[(((size_t)(b * NH + h)) * LQ + pix) * 64 + d] =
                        __float2bfloat16(v);
                } else if (MODE == 1) {
                    v += bias[col];
                    size_t o = (size_t)row * 384 + col;
                    ((float*)out0)[o] = resid[o] + gamma[col] * v;
                } else {
                    if (col < 48)
                        ((float*)out0)[(size_t)row * 48 + col] = v + bias[col];
                    else if (col < 72)
                        ((float*)out1)[(size_t)row * 24 + (col - 48)] = v + bias2[col - 48];
                }
            }
        }
    }
}

// ---------------------------------------------------------------------------
// Kernel 4: loc transform + softmax -> packed task-major sample table.
//   smp[((bh*LQ)+q)*4 + p] = {x_scaled, y_scaled, attw, 0}
// ---------------------------------------------------------------------------
__global__ __launch_bounds__(256) void locsoftmax_kernel(
    const float* __restrict__ offbuf, const float* __restrict__ attbuf,
    const float* __restrict__ refpts, float4* __restrict__ smp)
{
    int gid = blockIdx.x * blockDim.x + threadIdx.x;
    int row = gid / NH;
    int h   = gid % NH;
    int b   = row / LQ, q = row - b * LQ;
    size_t task = (size_t)(b * NH + h) * LQ + q;

    const float rx = refpts[row * 2 + 0];
    const float ry = refpts[row * 2 + 1];

    const float* off = offbuf + (size_t)row * (NH * NPTS * 2) + h * (NPTS * 2);
    const float* att = attbuf + (size_t)row * (NH * NPTS)     + h * NPTS;

    float l0 = att[0], l1 = att[1], l2 = att[2], l3 = att[3];
    float m  = fmaxf(fmaxf(l0, l1), fmaxf(l2, l3));
    float e[4] = {expf(l0 - m), expf(l1 - m), expf(l2 - m), expf(l3 - m)};
    float inv = 1.f / (e[0] + e[1] + e[2] + e[3]);

#pragma unroll
    for (int p = 0; p < NPTS; ++p) {
        float x = (rx + off[p * 2 + 0] * (1.f / W0)) * (float)W0 - 0.5f;
        float y = (ry + off[p * 2 + 1] * (1.f / H0)) * (float)H0 - 0.5f;
        smp[task * 4 + p] = make_float4(x, y, e[p] * inv, 0.f);
    }
}

// ---------------------------------------------------------------------------
// Kernel 5: deformable sampling, 4 tasks per wave.
//   lane = slot*16 + c4 ; slot = which of 4 consecutive q (same b,h plane);
//   c4 = channel group (4 bf16 = 8 B per tap-load). Clamp-index +
//   zero-weight for OOB (matches reference clip+mask semantics).
// ---------------------------------------------------------------------------
__global__ __launch_bounds__(256) void sample_kernel(
    const __hip_bfloat16* __restrict__ vt,   // (bh, pix, 64) bf16
    const float4* __restrict__ smp,          // (task, 4) {x,y,w,_}
    __hip_bfloat16* __restrict__ out)        // (row, 384) bf16
{
    const int wave = threadIdx.x >> 6, lane = threadIdx.x & 63;
    const int slot = lane >> 4;
    const int c4   = lane & 15;
    const int task = (blockIdx.x * 4 + wave) * 4 + slot;
    const int bh   = task / LQ;              // wave-uniform (LQ % 4 == 0)
    const int q    = task - bh * LQ;
    const int b    = bh / NH, h = bh - b * NH;

    const __hip_bfloat16* vbase = vt + (size_t)bh * LQ * 64;   // uniform base

    float a0 = 0.f, a1 = 0.f, a2 = 0.f, a3 = 0.f;

#pragma unroll
    for (int p = 0; p < NPTS; ++p) {
        float4 s = smp[(size_t)task * 4 + p];
        float x = s.x, y = s.y, wgt = s.z;
        float xf = floorf(x), yf = floorf(y);
        int   x0 = (int)xf,   y0 = (int)yf;
        float fx = x - xf,    fy = y - yf;
        float gx0 = 1.f - fx, gx1 = fx;
        float gy0w = (1.f - fy) * wgt, gy1w = fy * wgt;

#pragma unroll
        for (int cy = 0; cy < 2; ++cy) {
            const int   yi = y0 + cy;
            const float wy = cy ? gy1w : gy0w;
            const bool  vy = (unsigned)yi < H0;
            const int   yc = min(max(yi, 0), H0 - 1);
#pragma unroll
            for (int cx = 0; cx < 2; ++cx) {
                const int xi = x0 + cx;
                float wc = wy * (cx ? gx1 : gx0);
                if (!vy || (unsigned)xi >= W0) wc = 0.f;
                const int xc = min(max(xi, 0), W0 - 1);
                const uint2 raw = *(const uint2*)(vbase + (size_t)(yc * W0 + xc) * 64 + c4 * 4);
                a0 = fmaf(wc, bf_lo(raw.x), a0);
                a1 = fmaf(wc, bf_hi(raw.x), a1);
                a2 = fmaf(wc, bf_lo(raw.y), a2);
                a3 = fmaf(wc, bf_hi(raw.y), a3);
            }
        }
    }

    const int row = b * LQ + q;
    __hip_bfloat162 o01, o23;
    o01.x = __float2bfloat16(a0); o01.y = __float2bfloat16(a1);
    o23.x = __float2bfloat16(a2); o23.y = __float2bfloat16(a3);
    __hip_bfloat162* op = (__hip_bfloat162*)(out + (size_t)row * DIM + h * HD + c4 * 4);
    op[0] = o01;
    op[1] = o23;
}

// ---------------------------------------------------------------------------
// Launch
// ---------------------------------------------------------------------------
extern "C" void kernel_launch(void* const* d_in, const int* in_sizes, int n_in,
                              void* d_out, int out_size, void* d_ws, size_t ws_size,
                              hipStream_t stream)
{
    const float* query   = (const float*)d_in[0];
    const float* refpts  = (const float*)d_in[1];
    const float* feat    = (const float*)d_in[2];
    const float* qn_w    = (const float*)d_in[5];
    const float* qn_b    = (const float*)d_in[6];
    const float* fn_w    = (const float*)d_in[7];
    const float* fn_b    = (const float*)d_in[8];
    const float* w_value = (const float*)d_in[9];
    const float* b_value = (const float*)d_in[10];
    const float* w_off   = (const float*)d_in[11];
    const float* b_off   = (const float*)d_in[12];
    const float* w_attn  = (const float*)d_in[13];
    const float* b_attn  = (const float*)d_in[14];
    const float* w_out   = (const float*)d_in[15];
    const float* b_out   = (const float*)d_in[16];
    const float* gamma   = (const float*)d_in[17];

    char* wsb = (char*)d_ws;
    __hip_bfloat16* Q16    = (__hip_bfloat16*)wsb;                 // 56.6 MB
    __hip_bfloat16* F16    = (__hip_bfloat16*)(wsb + 56623104);    // 56.6 MB
    __hip_bfloat16* vtrans = (__hip_bfloat16*)(wsb + 113246208);   // 56.6 MB
    __hip_bfloat16* att16  = (__hip_bfloat16*)(wsb + 169869312);   // 56.6 MB
    float*          offbuf = (float*)(wsb + 226492416);            // 14.2 MB
    float*          attbuf = (float*)(wsb + 240648192);            // 7.1 MB
    __hip_bfloat16* WtV    = (__hip_bfloat16*)(wsb + 247726080);   // 294912 B
    __hip_bfloat16* WtO    = (__hip_bfloat16*)(wsb + 248020992);   // 294912 B
    __hip_bfloat16* WtS    = (__hip_bfloat16*)(wsb + 248315904);   // 98304 B
    float4*         smp    = (float4*)wsb;  // aliases Q16 (dead after MODE2 GEMM)
    float* outp = (float*)d_out;

    // 1-2. LayerNorms -> bf16
    lnorm_kernel<<<NROWS / 4, 256, 0, stream>>>(query, qn_w, qn_b, Q16);
    lnorm_kernel<<<NROWS / 4, 256, 0, stream>>>(feat,  fn_w, fn_b, F16);

    // 3. weight transpose/cvt
    wtrans_kernel<<<1344, 256, 0, stream>>>(w_value, w_out, w_off, w_attn,
                                            WtV, WtO, WtS);

    // 4. value = LN(feat) @ w_value + b_value  -> bf16 (b,h,pix,64) layout
    gemm16_kernel<0><<<dim3(NROWS / 128, 3), 256, 0, stream>>>(
        F16, WtV, b_value, nullptr, nullptr, nullptr, vtrans, nullptr);

    // 5. off/attn logits = LN(q) @ [w_off|w_attn]  (one 128-col MFMA GEMM)
    gemm16_kernel<2><<<dim3(NROWS / 128, 1), 256, 0, stream>>>(
        Q16, WtS, b_off, b_attn, nullptr, nullptr, offbuf, attbuf);

    // 6. sample coords + softmax -> packed task-major table (over dead Q16)
    locsoftmax_kernel<<<(NROWS * NH) / 256, 256, 0, stream>>>(
        offbuf, attbuf, refpts, smp);

    // 7. deformable bilinear sampling, 4 tasks/wave -> bf16 attn_out
    sample_kernel<<<(NROWS * NH) / 16, 256, 0, stream>>>(
        vtrans, smp, att16);

    // 8. out = query + gamma * (attn_out @ w_out + b_out)
    gemm16_kernel<1><<<dim3(NROWS / 128, 3), 256, 0, stream>>>(
        att16, WtO, b_out, nullptr, query, gamma, outp, nullptr);
}